// Round 1
// baseline (129.081 us; speedup 1.0000x reference)
//
#include <hip/hip_runtime.h>
#include <math.h>

// PhyGate: elementwise physics gate over B rows of (b, v[3], w[3]).
// 4 rows per thread -> exact float4 vectorization of the (B,3) layout.

__global__ __launch_bounds__(256) void phygate_kernel(
    const float* __restrict__ b,
    const float* __restrict__ v,
    const float* __restrict__ w,
    const float* __restrict__ dt_p,
    const float* __restrict__ lin_w_p,
    const float* __restrict__ lin_b_p,
    const float* __restrict__ p1_p,
    const float* __restrict__ p2_p,
    const float* __restrict__ p3_p,
    const float* __restrict__ p4_p,
    const float* __restrict__ p5_p,
    const float* __restrict__ p6_p,
    float* __restrict__ out_v,   // B*3 floats
    float* __restrict__ out_w,   // B*3 floats
    int B)
{
    const float dt  = dt_p[0];
    const float lw  = lin_w_p[0];
    const float lb  = lin_b_p[0];
    const float p1  = p1_p[0];
    const float p2  = p2_p[0];
    const float p3x = p3_p[0], p3y = p3_p[1], p3z = p3_p[2];
    const float p4  = p4_p[0];
    const float p5  = p5_p[0];
    const float r   = p6_p[0];
    const float coef = p4 * (1.0f + p5);

    const int tid = blockIdx.x * blockDim.x + threadIdx.x;
    const long long i0 = 4LL * tid;
    if (i0 >= B) return;

    float vf[12], wf[12], bf4[4], ovf[12], owf[12];
    int nrows;

    if (i0 + 4 <= B) {
        nrows = 4;
        const float4* b4 = (const float4*)b;
        const float4* v4 = (const float4*)v;
        const float4* w4 = (const float4*)w;
        float4 bb = b4[tid];
        bf4[0] = bb.x; bf4[1] = bb.y; bf4[2] = bb.z; bf4[3] = bb.w;
        float4 a0 = v4[3LL*tid+0], a1 = v4[3LL*tid+1], a2 = v4[3LL*tid+2];
        vf[0]=a0.x; vf[1]=a0.y; vf[2]=a0.z; vf[3]=a0.w;
        vf[4]=a1.x; vf[5]=a1.y; vf[6]=a1.z; vf[7]=a1.w;
        vf[8]=a2.x; vf[9]=a2.y; vf[10]=a2.z; vf[11]=a2.w;
        float4 c0 = w4[3LL*tid+0], c1 = w4[3LL*tid+1], c2 = w4[3LL*tid+2];
        wf[0]=c0.x; wf[1]=c0.y; wf[2]=c0.z; wf[3]=c0.w;
        wf[4]=c1.x; wf[5]=c1.y; wf[6]=c1.z; wf[7]=c1.w;
        wf[8]=c2.x; wf[9]=c2.y; wf[10]=c2.z; wf[11]=c2.w;
    } else {
        nrows = (int)(B - i0);
        for (int j = 0; j < nrows; ++j) {
            bf4[j] = b[i0 + j];
            for (int k = 0; k < 3; ++k) {
                vf[3*j+k] = v[3*(i0+j)+k];
                wf[3*j+k] = w[3*(i0+j)+k];
            }
        }
    }

    #pragma unroll
    for (int j = 0; j < 4; ++j) {
        float vx = vf[3*j], vy = vf[3*j+1], vz = vf[3*j+2];
        float wx = wf[3*j], wy = wf[3*j+1], wz = wf[3*j+2];

        float g1 = 1.0f / (1.0f + expf(-(bf4[j]*lw + lb)));
        float g2 = 1.0f - g1;

        float dx = vx - wy * r;
        float dy = vy + wx * r;
        float al = coef * fabsf(vz) / sqrtf(dx*dx + dy*dy + 1e-6f);
        al = fminf(al, 0.4f);

        float oma  = 1.0f - al;
        float vbx  = oma * vx + al * r * wy;
        float vby  = oma * vy - al * r * wx;
        float vbz  = -p5 * vz;

        float c    = 1.5f * al / r;
        float om15 = 1.0f - 1.5f * al;
        float wbx  = -c * vy + om15 * wx;
        float wby  =  c * vx + om15 * wy;
        float wbz  = wz;

        float v2x = g1*vx + g2*vbx;
        float v2y = g1*vy + g2*vby;
        float v2z = g1*vz + g2*vbz;
        float w2x = g1*wx + g2*wbx;
        float w2y = g1*wy + g2*wby;
        float w2z = g1*wz + g2*wbz;

        float nv = sqrtf(v2x*v2x + v2y*v2y + v2z*v2z);
        // cross(w2, v2)
        float cx = w2y*v2z - w2z*v2y;
        float cy = w2z*v2x - w2x*v2z;
        float cz = w2x*v2y - w2y*v2x;

        float ax = -p1*nv*v2x + p2*cx + p3x;
        float ay = -p1*nv*v2y + p2*cy + p3y;
        float az = -p1*nv*v2z + p2*cz + p3z - 9.81f;

        ovf[3*j]   = v2x + ax*dt;
        ovf[3*j+1] = v2y + ay*dt;
        ovf[3*j+2] = v2z + az*dt;
        owf[3*j]   = w2x;
        owf[3*j+1] = w2y;
        owf[3*j+2] = w2z;
    }

    if (nrows == 4) {
        float4* ov4 = (float4*)out_v;
        float4* ow4 = (float4*)out_w;
        ov4[3LL*tid+0] = make_float4(ovf[0], ovf[1], ovf[2],  ovf[3]);
        ov4[3LL*tid+1] = make_float4(ovf[4], ovf[5], ovf[6],  ovf[7]);
        ov4[3LL*tid+2] = make_float4(ovf[8], ovf[9], ovf[10], ovf[11]);
        ow4[3LL*tid+0] = make_float4(owf[0], owf[1], owf[2],  owf[3]);
        ow4[3LL*tid+1] = make_float4(owf[4], owf[5], owf[6],  owf[7]);
        ow4[3LL*tid+2] = make_float4(owf[8], owf[9], owf[10], owf[11]);
    } else {
        for (int j = 0; j < nrows; ++j) {
            for (int k = 0; k < 3; ++k) {
                out_v[3*(i0+j)+k] = ovf[3*j+k];
                out_w[3*(i0+j)+k] = owf[3*j+k];
            }
        }
    }
}

extern "C" void kernel_launch(void* const* d_in, const int* in_sizes, int n_in,
                              void* d_out, int out_size, void* d_ws, size_t ws_size,
                              hipStream_t stream) {
    const float* b     = (const float*)d_in[0];
    const float* v     = (const float*)d_in[1];
    const float* w     = (const float*)d_in[2];
    const float* dt    = (const float*)d_in[3];
    const float* lin_w = (const float*)d_in[4];
    const float* lin_b = (const float*)d_in[5];
    const float* p1    = (const float*)d_in[6];
    const float* p2    = (const float*)d_in[7];
    const float* p3    = (const float*)d_in[8];
    const float* p4    = (const float*)d_in[9];
    const float* p5    = (const float*)d_in[10];
    const float* p6    = (const float*)d_in[11];

    const int B = in_sizes[0];           // b has B elements
    float* out_v = (float*)d_out;        // first output: v_new, B*3 floats
    float* out_w = out_v + (size_t)3*B;  // second output: w2, B*3 floats

    const int threads = 256;
    const int nthreads_needed = (B + 3) / 4;
    const int blocks = (nthreads_needed + threads - 1) / threads;

    phygate_kernel<<<blocks, threads, 0, stream>>>(
        b, v, w, dt, lin_w, lin_b, p1, p2, p3, p4, p5, p6, out_v, out_w, B);
}